// Round 4
// baseline (104.234 us; speedup 1.0000x reference)
//
#include <hip/hip_runtime.h>
#include <math.h>

// Both clouds: 16384 x float2.
#define NPTS  16384
#define BLK   256
#define Q     8                      // queries per thread (strided -- R2 best)
#define QB    (NPTS / (BLK * Q))     // 8 query-blocks per direction
#define TCH   64                     // target chunks per direction
#define CHUNK (NPTS / TCH)           // 256 targets per chunk
#define G4    (CHUNK / 4)            // 64 groups of 4 targets per chunk
#define NG    (NPTS / 4)             // 4096 groups per direction

// ws layout:
//   [0, 8 MB):  partials  part[ch][dir*NPTS + q]  (TCH * 2*NPTS floats)
//   [8 MB, +768 KB): packed target table, per group of 4 targets:
//        3 x float4 = { (-2x0,-2y0,-2x1,-2y1), (-2x2,-2y2,-2x3,-2y3),
//                       (z0,z1,z2,z3) },  z = x^2+y^2
// Every partial slot is written exactly once (no init / no atomics needed);
// the table is written by cc_pack_kernel before cc_min_kernel reads it
// (same stream). Harness poison is always overwritten before read.
#define PART_FLOATS (TCH * 2 * NPTS)

// Round-4 theory: target data is WAVE-UNIFORM, so it belongs in the scalar
// pipe, not LDS. Table reads below use blockIdx/loop-derived (uniform)
// addresses -> compiler emits s_load_dwordx4 into SGPRs; inner-loop FMAs use
// at most one SGPR operand each (legal), VALU stream unchanged. LDS, the
// block-start LDS fill, and __syncthreads are gone entirely.

__global__ __launch_bounds__(BLK) void cc_pack_kernel(
        const float2* __restrict__ pc,    // render points (targets for dir=1)
        const float2* __restrict__ ref,   // ref points    (targets for dir=0)
        float* __restrict__ ws,
        float* __restrict__ out) {
    int idx = blockIdx.x * BLK + threadIdx.x;   // 0 .. 2*NG-1
    if (idx == 0) out[0] = 0.0f;
    int dir = idx / NG;
    int g   = idx - dir * NG;
    const float4* src = (const float4*)(dir ? pc : ref);
    float4 p01 = src[2 * g];       // (x0, y0, x1, y1)
    float4 p23 = src[2 * g + 1];   // (x2, y2, x3, y3)
    float4* tb = (float4*)(ws + PART_FLOATS) + (size_t)idx * 3;
    tb[0] = make_float4(-2.0f * p01.x, -2.0f * p01.y,
                        -2.0f * p01.z, -2.0f * p01.w);
    tb[1] = make_float4(-2.0f * p23.x, -2.0f * p23.y,
                        -2.0f * p23.z, -2.0f * p23.w);
    tb[2] = make_float4(fmaf(p01.x, p01.x, p01.y * p01.y),
                        fmaf(p01.z, p01.z, p01.w * p01.w),
                        fmaf(p23.x, p23.x, p23.y * p23.y),
                        fmaf(p23.z, p23.z, p23.w * p23.w));
}

__global__ __launch_bounds__(BLK, 4) void cc_min_kernel(
        const float2* __restrict__ pc,    // render points (16384)
        const float2* __restrict__ ref,   // ref points    (16384)
        float* __restrict__ ws) {
    int b   = blockIdx.x;
    int dir = b / (QB * TCH);
    int rem = b % (QB * TCH);
    int qb  = rem / TCH;
    int ch  = rem % TCH;

    const float2* __restrict__ qry = dir ? ref : pc;

    // Uniform table base for this block's target chunk; readfirstlane is
    // insurance that the compiler proves uniformity -> s_load path.
    int tbase = __builtin_amdgcn_readfirstlane(3 * (dir * NG + ch * G4));
    const float4* __restrict__ tbl = (const float4*)(ws + PART_FLOATS);

    // Q queries per thread (coalesced, stride BLK)
    float px[Q], py[Q], pn[Q], m[Q];
    int qbase = qb * (BLK * Q) + threadIdx.x;
#pragma unroll
    for (int j = 0; j < Q; ++j) {
        float2 p = qry[qbase + j * BLK];
        px[j] = p.x;
        py[j] = p.y;
        pn[j] = fmaf(p.x, p.x, p.y * p.y);
        m[j]  = INFINITY;
    }

    // Surrogate s = |t|^2 - 2q.t.  Per 4 targets per query: 8 FMA + 2 min3.
    // A,B land in SGPRs (free scalar pipe); z's need one v_mov each
    // (amortized over Q queries) since each FMA admits only 1 SGPR operand.
#pragma unroll 4
    for (int g = 0; g < G4; ++g) {
        float4 A = tbl[tbase + 3 * g];       // s_load_dwordx4 (uniform)
        float4 B = tbl[tbase + 3 * g + 1];
        float4 Z = tbl[tbase + 3 * g + 2];
        float z0 = Z.x, z1 = Z.y, z2 = Z.z, z3 = Z.w;
#pragma unroll
        for (int j = 0; j < Q; ++j) {
            float s0 = fmaf(px[j], A.x, fmaf(py[j], A.y, z0));
            float s1 = fmaf(px[j], A.z, fmaf(py[j], A.w, z1));
            float s2 = fmaf(px[j], B.x, fmaf(py[j], B.y, z2));
            float s3 = fmaf(px[j], B.z, fmaf(py[j], B.w, z3));
            m[j] = fminf(fminf(m[j], s0), s1);   // -> v_min3_f32
            m[j] = fminf(fminf(m[j], s2), s3);   // -> v_min3_f32
        }
    }

    // d^2 = max(min_surrogate + |p|^2, 0); coalesced strided stores of this
    // block's partial min -- combine happens in cc_final_kernel.
    float* wrow = ws + (size_t)ch * (2 * NPTS) + dir * NPTS + qbase;
#pragma unroll
    for (int j = 0; j < Q; ++j) {
        wrow[j * BLK] = fmaxf(m[j] + pn[j], 0.0f);
    }
}

// Parallel finish: one thread per (dir,query), 256 blocks x 128 threads.
// 16 independent accumulators -> 16 outstanding loads per batch (4 batches),
// then tree-min, sqrt, wave reduce, one atomicAdd/wave.
#define FBLK 128
__global__ __launch_bounds__(FBLK) void cc_final_kernel(
        const float* __restrict__ ws, float* __restrict__ out) {
    int q = blockIdx.x * FBLK + threadIdx.x;   // 0 .. 2*NPTS-1

    float mm[16];
#pragma unroll
    for (int k = 0; k < 16; ++k)
        mm[k] = ws[(size_t)k * (2 * NPTS) + q];
#pragma unroll
    for (int ch = 16; ch < TCH; ch += 16) {
#pragma unroll
        for (int k = 0; k < 16; ++k)
            mm[k] = fminf(mm[k], ws[(size_t)(ch + k) * (2 * NPTS) + q]);
    }
#pragma unroll
    for (int s2 = 8; s2 > 0; s2 >>= 1)
#pragma unroll
        for (int k = 0; k < 8; ++k)
            if (k < s2) mm[k] = fminf(mm[k], mm[k + s2]);

    float s = sqrtf(mm[0]);

#pragma unroll
    for (int off = 32; off > 0; off >>= 1)
        s += __shfl_down(s, off, 64);

    if ((threadIdx.x & 63) == 0)
        atomicAdd(out, s);
}

extern "C" void kernel_launch(void* const* d_in, const int* in_sizes, int n_in,
                              void* d_out, int out_size, void* d_ws, size_t ws_size,
                              hipStream_t stream) {
    const float2* pc  = (const float2*)d_in[0];  // img_render_points (128*128*2 f32)
    const float2* ref = (const float2*)d_in[1];  // ref contour (16384*2 f32)
    float* out = (float*)d_out;
    float* ws  = (float*)d_ws;                   // 8 MB partials + 768 KB table

    cc_pack_kernel<<<(2 * NG) / BLK, BLK, 0, stream>>>(pc, ref, ws, out);
    // 2 dirs x 8 query-blocks x 64 chunks = 1024 blocks = 4/CU resident
    cc_min_kernel<<<2 * QB * TCH, BLK, 0, stream>>>(pc, ref, ws);
    cc_final_kernel<<<(2 * NPTS) / FBLK, FBLK, 0, stream>>>(ws, out);
}

// Round 5
// 87.235 us; speedup vs baseline: 1.1949x; 1.1949x over previous
//
#include <hip/hip_runtime.h>
#include <math.h>

// Both clouds: 16384 x float2. Chamfer via MFMA on the matrix pipe.
//
// d^2(q,t) = |q|^2 + (|t|^2 - 2 q.t). The parenthesized surrogate is a
// rank-8 dot product in f16 hi/lo split precision:
//   A(query)  = (hx, hx, lx, hy, hy, ly, 1, 1)
//   B(target) = (-2htx, -2ltx, -2htx, -2hty, -2lty, -2hty, hz, lz)
// with x = hx + lx (f16 split, coords pre-scaled by 16 to avoid f16
// denormals; residual error in d^2 ~1e-5 unscaled). K=8 of the MFMA's K=32
// is used; A's k>=8 slots (lanes 16-63) are ZEROED so B's k>=8 garbage
// cannot contribute. |q|^2 is added in the final kernel (min is invariant
// to the per-query constant).
//
// mfma_f32_16x16x32_f16: D[16q x 16t]; C/D layout col=lane&15 (target),
// row=(lane>>4)*4+reg (query) [m89-verified, dtype-independent].

#define NPTS  16384
#define BLK   256
#define TCH   16                    // target chunks per direction
#define CHUNK (NPTS / TCH)          // 1024 targets per chunk
#define TT    (CHUNK / 16)          // 64 target tiles per chunk
#define QPB   512                   // queries per block (4 waves x 8 qtiles x 16)
#define QBN   (NPTS / QPB)          // 32 query blocks per direction
#define SCALE 16.0f
#define INVS  0.0625f

typedef _Float16 f16x8 __attribute__((ext_vector_type(8)));
typedef float    f32x4 __attribute__((ext_vector_type(4)));

// ws layout: part[ch][dir*NPTS + q] = per-chunk min SURROGATE (scaled) for
// query q. TCH * 2*NPTS * 4 B = 2 MB. Every slot written exactly once by
// block (dir,qblk,ch) -> no init, no atomics; poison is overwritten.

__global__ __launch_bounds__(BLK, 4) void cc_min_kernel(
        const float2* __restrict__ pc,    // render points (16384)
        const float2* __restrict__ ref,   // ref points    (16384)
        float* __restrict__ ws,
        float* __restrict__ out) {
    __shared__ f16x8 sB[CHUNK];          // 16 KB packed B payloads

    const int b    = blockIdx.x;
    const int dir  = b / (QBN * TCH);
    const int rem  = b % (QBN * TCH);
    const int qblk = rem / TCH;
    const int ch   = rem % TCH;
    const int tid  = threadIdx.x;
    const int wid  = tid >> 6;
    const int lane = tid & 63;

    if (b == 0 && tid == 0) out[0] = 0.0f;

    const float2* __restrict__ qry = dir ? ref : pc;
    const float2* __restrict__ tgt = dir ? pc  : ref;

    // ---- stage packed B payloads (f16 hi/lo split, coords pre-scaled) ----
#pragma unroll
    for (int r = 0; r < CHUNK / BLK; ++r) {
        int i = r * BLK + tid;
        float2 t = tgt[ch * CHUNK + i];
        float xs = t.x * SCALE, ys = t.y * SCALE;
        _Float16 hx = (_Float16)xs; _Float16 lx = (_Float16)(xs - (float)hx);
        _Float16 hy = (_Float16)ys; _Float16 ly = (_Float16)(ys - (float)hy);
        float zz = fmaf(xs, xs, ys * ys);
        _Float16 hz = (_Float16)zz; _Float16 lz = (_Float16)(zz - (float)hz);
        f16x8 p;
        p[0] = (_Float16)(-2.0f * (float)hx);   // exact: f16 exponent bump
        p[1] = (_Float16)(-2.0f * (float)lx);
        p[2] = p[0];
        p[3] = (_Float16)(-2.0f * (float)hy);
        p[4] = (_Float16)(-2.0f * (float)ly);
        p[5] = p[3];
        p[6] = hz;
        p[7] = lz;
        sB[i] = p;                           // ds_write_b128
    }

    // ---- A fragments: 8 query-tiles per wave; lanes>=16 MUST be zero ----
    const int q0 = qblk * QPB + wid * 128;
    f16x8 A[8];
#pragma unroll
    for (int qt = 0; qt < 8; ++qt) {
        f16x8 a;
#pragma unroll
        for (int e = 0; e < 8; ++e) a[e] = (_Float16)0.0f;
        if (lane < 16) {
            float2 qp = qry[q0 + qt * 16 + lane];
            float xs = qp.x * SCALE, ys = qp.y * SCALE;
            _Float16 hx = (_Float16)xs; _Float16 lx = (_Float16)(xs - (float)hx);
            _Float16 hy = (_Float16)ys; _Float16 ly = (_Float16)(ys - (float)hy);
            a[0] = hx; a[1] = hx; a[2] = lx;
            a[3] = hy; a[4] = hy; a[5] = ly;
            a[6] = (_Float16)1.0f; a[7] = (_Float16)1.0f;
        }
        A[qt] = a;
    }
    __syncthreads();

    // ---- MFMA main loop: 8 qtiles x 64 ttiles = 512 MFMA per wave ----
    f32x4 m[8];
#pragma unroll
    for (int qt = 0; qt < 8; ++qt)
        m[qt] = (f32x4){INFINITY, INFINITY, INFINITY, INFINITY};

    const f32x4 Z4 = (f32x4){0.f, 0.f, 0.f, 0.f};
    const int bo = lane & 15;               // lanes 16-63 read copies (bcast);
                                            // their garbage k>=8 hits A-zeros
    for (int tt = 0; tt < TT; tt += 2) {
        f16x8 b0 = sB[tt * 16 + bo];        // ds_read_b128
        f16x8 b1 = sB[tt * 16 + 16 + bo];
#pragma unroll
        for (int qt = 0; qt < 8; ++qt) {
            f32x4 d0 = __builtin_amdgcn_mfma_f32_16x16x32_f16(A[qt], b0, Z4, 0, 0, 0);
            f32x4 d1 = __builtin_amdgcn_mfma_f32_16x16x32_f16(A[qt], b1, Z4, 0, 0, 0);
#pragma unroll
            for (int r = 0; r < 4; ++r)     // 4 x v_min3 per 2 MFMA
                m[qt][r] = fminf(fminf(m[qt][r], d0[r]), d1[r]);
        }
    }

    // ---- cross-lane min over the 16 target-columns in each 16-lane group ----
#pragma unroll
    for (int qt = 0; qt < 8; ++qt) {
#pragma unroll
        for (int r = 0; r < 4; ++r) {
            float v = m[qt][r];
            v = fminf(v, __shfl_xor(v, 1, 16));
            v = fminf(v, __shfl_xor(v, 2, 16));
            v = fminf(v, __shfl_xor(v, 4, 16));
            v = fminf(v, __shfl_xor(v, 8, 16));
            m[qt][r] = v;
        }
    }

    // leader lane of each 16-group holds rows (lane>>4)*4 + r -> float4 store
    if ((lane & 15) == 0) {
        int rowbase = (lane >> 4) * 4;
        float* prow = ws + (size_t)ch * (2 * NPTS) + dir * NPTS;
#pragma unroll
        for (int qt = 0; qt < 8; ++qt) {
            float4 v = make_float4(m[qt][0], m[qt][1], m[qt][2], m[qt][3]);
            *(float4*)(prow + q0 + qt * 16 + rowbase) = v;
        }
    }
}

// Finish: one thread per (dir,query): 16-chunk min + |q|^2 + clamp + sqrt,
// unscale, wave reduce, one atomicAdd per wave.
__global__ __launch_bounds__(BLK) void cc_final_kernel(
        const float2* __restrict__ pc, const float2* __restrict__ ref,
        const float* __restrict__ ws, float* __restrict__ out) {
    int q = blockIdx.x * BLK + threadIdx.x;   // 0 .. 2*NPTS-1

    float m0 = INFINITY, m1 = INFINITY, m2 = INFINITY, m3 = INFINITY;
#pragma unroll
    for (int ch = 0; ch < TCH; ch += 4) {
        m0 = fminf(m0, ws[(size_t)(ch + 0) * (2 * NPTS) + q]);
        m1 = fminf(m1, ws[(size_t)(ch + 1) * (2 * NPTS) + q]);
        m2 = fminf(m2, ws[(size_t)(ch + 2) * (2 * NPTS) + q]);
        m3 = fminf(m3, ws[(size_t)(ch + 3) * (2 * NPTS) + q]);
    }
    float msur = fminf(fminf(m0, m1), fminf(m2, m3));

    int dir = q >> 14, qi = q & (NPTS - 1);
    float2 p = dir ? ref[qi] : pc[qi];
    float pn = (SCALE * SCALE) * fmaf(p.x, p.x, p.y * p.y);  // scaled |q|^2
    float s = sqrtf(fmaxf(msur + pn, 0.0f)) * INVS;

#pragma unroll
    for (int off = 32; off > 0; off >>= 1)
        s += __shfl_down(s, off, 64);

    if ((threadIdx.x & 63) == 0)
        atomicAdd(out, s);
}

extern "C" void kernel_launch(void* const* d_in, const int* in_sizes, int n_in,
                              void* d_out, int out_size, void* d_ws, size_t ws_size,
                              hipStream_t stream) {
    const float2* pc  = (const float2*)d_in[0];  // img_render_points (128*128*2 f32)
    const float2* ref = (const float2*)d_in[1];  // ref contour (16384*2 f32)
    float* out = (float*)d_out;
    float* ws  = (float*)d_ws;                   // 2 MB used

    // 2 dirs x 32 query-blocks x 16 chunks = 1024 blocks = 4/CU, no tail
    cc_min_kernel<<<2 * QBN * TCH, BLK, 0, stream>>>(pc, ref, ws, out);
    cc_final_kernel<<<(2 * NPTS) / BLK, BLK, 0, stream>>>(pc, ref, ws, out);
}

// Round 6
// 85.085 us; speedup vs baseline: 1.2251x; 1.0253x over previous
//
#include <hip/hip_runtime.h>
#include <math.h>

// Both clouds: 16384 x float2. Chamfer via MFMA, single fused pass.
//
// d^2(q,t) = |q|^2 + (|t|^2 - 2 q.t). Surrogate is a rank-8 f16 hi/lo dot:
//   A(query)  = (hx, hx, lx, hy, hy, ly, 1, 1)           (k = 0..7)
//   B(target) = (-2htx, -2ltx, -2htx, -2hty, -2lty, -2hty, hz, lz)
// coords pre-scaled by 16 (no f16 denormals). A lanes>=16 (k>=8) are ZERO so
// B's k>=8 garbage cannot contribute. Layout + split verified in round 5
// (absmax 0.0). mfma_f32_16x16x32_f16: col=lane&15 (target),
// row=(lane>>4)*4+reg (query).

#define NPTS  16384
#define BLK   512                   // 8 waves
#define QPB   64                    // queries per block (4 qtiles)
#define NCH   16                    // target chunks
#define CH    1024                  // targets per chunk (64 ttiles)
#define SCALE 16.0f
#define INVS  0.0625f

typedef _Float16 f16x8 __attribute__((ext_vector_type(8)));
typedef float    f32x4 __attribute__((ext_vector_type(4)));

// ws: packed target table only. tbl[dir*NPTS + i], 16 B each -> 512 KB.
// Written by cc_pack before cc_min reads it (stream order). No partials.

__device__ __forceinline__ void gload16(const void* g, void* l) {
    __builtin_amdgcn_global_load_lds(
        (const __attribute__((address_space(1))) unsigned int*)g,
        (__attribute__((address_space(3))) unsigned int*)l, 16, 0, 0);
}

__global__ __launch_bounds__(256) void cc_pack_kernel(
        const float2* __restrict__ pc, const float2* __restrict__ ref,
        f16x8* __restrict__ tbl, float* __restrict__ out) {
    int idx = blockIdx.x * 256 + threadIdx.x;   // 0 .. 2*NPTS-1
    if (idx == 0) out[0] = 0.0f;
    int dir = idx >> 14;
    int i   = idx & (NPTS - 1);
    float2 t = dir ? pc[i] : ref[i];            // dir0 targets = ref
    float xs = t.x * SCALE, ys = t.y * SCALE;
    _Float16 hx = (_Float16)xs; _Float16 lx = (_Float16)(xs - (float)hx);
    _Float16 hy = (_Float16)ys; _Float16 ly = (_Float16)(ys - (float)hy);
    float zz = fmaf(xs, xs, ys * ys);
    _Float16 hz = (_Float16)zz; _Float16 lz = (_Float16)(zz - (float)hz);
    f16x8 p;
    p[0] = (_Float16)(-2.0f * (float)hx);
    p[1] = (_Float16)(-2.0f * (float)lx);
    p[2] = p[0];
    p[3] = (_Float16)(-2.0f * (float)hy);
    p[4] = (_Float16)(-2.0f * (float)ly);
    p[5] = p[3];
    p[6] = hz;
    p[7] = lz;
    tbl[idx] = p;
}

// 512 blocks x 512 thr = 2 blocks/CU, 16 waves/CU = 4/SIMD.
// Wave w: qtile = w&3 (16 queries), target half = w>>2 (chunks half*8..+8).
// Each wave: 1 A-frag, 1 f32x4 accumulator, 512 MFMA total.
__global__ __launch_bounds__(BLK, 4) void cc_min_kernel(
        const float2* __restrict__ pc, const float2* __restrict__ ref,
        const f16x8* __restrict__ tbl, float* __restrict__ out) {
    // stage[buf] = [chunk c payloads (16 KB) | chunk 8+c payloads (16 KB)]
    __shared__ f16x8 stage[2][2 * CH];          // 64 KB
    __shared__ f32x4 xbuf[4][64];               // cross-half min exchange
    __shared__ float psum[16];

    const int b    = blockIdx.x;
    const int dir  = b >> 8;
    const int qblk = b & 255;
    const int tid  = threadIdx.x;
    const int w    = tid >> 6;
    const int lane = tid & 63;
    const int half = w >> 2;
    const int qt   = w & 3;

    const float2* __restrict__ qry = dir ? ref : pc;
    const f16x8*  __restrict__ tb  = tbl + dir * NPTS;

    // ---- A fragment: 16 queries, lanes>=16 zero (kills B's k>=8 garbage) --
    const int q0 = qblk * QPB + qt * 16;
    f16x8 A;
#pragma unroll
    for (int e = 0; e < 8; ++e) A[e] = (_Float16)0.0f;
    if (lane < 16) {
        float2 qp = qry[q0 + lane];
        float xs = qp.x * SCALE, ys = qp.y * SCALE;
        _Float16 hx = (_Float16)xs; _Float16 lx = (_Float16)(xs - (float)hx);
        _Float16 hy = (_Float16)ys; _Float16 ly = (_Float16)(ys - (float)hy);
        A[0] = hx; A[1] = hx; A[2] = lx;
        A[3] = hy; A[4] = hy; A[5] = ly;
        A[6] = (_Float16)1.0f; A[7] = (_Float16)1.0f;
    }

    // ---- async staging: chunk pair (c, 8+c) -> stage[buf] (32 KB) --------
    // Per wave 4 issues; LDS dest = uniform base (+ lane*16 by HW),
    // global src = per-lane. Issues 0,1 cover bytes [0,16K) (chunk c),
    // issues 2,3 cover [16K,32K) (chunk 8+c).
    const int lo = w * 1024;
#define STAGE(buf, c)                                                        \
    {                                                                        \
        const char* g0 = (const char*)(tb + (c) * CH);                       \
        const char* g1 = (const char*)(tb + (8 + (c)) * CH);                 \
        char* lb = (char*)&stage[buf][0];                                    \
        gload16(g0 + lo + lane * 16,          lb + lo);                      \
        gload16(g0 + lo + 8192 + lane * 16,   lb + lo + 8192);               \
        gload16(g1 + lo + lane * 16,          lb + lo + 16384);              \
        gload16(g1 + lo + 8192 + lane * 16,   lb + lo + 24576);              \
    }

    f32x4 m = (f32x4){INFINITY, INFINITY, INFINITY, INFINITY};
    const f32x4 Z4 = (f32x4){0.f, 0.f, 0.f, 0.f};
    const int bo = lane & 15;

    STAGE(0, 0);
    __syncthreads();                 // implicit vmcnt(0): buf0 ready

    for (int c = 0; c < 8; ++c) {
        if (c < 7) STAGE((c + 1) & 1, c + 1);   // prefetch under compute
        const f16x8* S = &stage[c & 1][half * CH];
#pragma unroll 8
        for (int tt = 0; tt < 64; tt += 2) {
            f16x8 b0 = S[tt * 16 + bo];          // ds_read_b128
            f16x8 b1 = S[tt * 16 + 16 + bo];
            f32x4 d0 = __builtin_amdgcn_mfma_f32_16x16x32_f16(A, b0, Z4, 0, 0, 0);
            f32x4 d1 = __builtin_amdgcn_mfma_f32_16x16x32_f16(A, b1, Z4, 0, 0, 0);
#pragma unroll
            for (int r = 0; r < 4; ++r)          // v_min3 per MFMA pair
                m[r] = fminf(fminf(m[r], d0[r]), d1[r]);
        }
        __syncthreads();             // readers done + prefetch drained
    }

    // ---- cross-half combine: wave w (half 0) with wave w+4 (half 1) ------
    if (half) *(f32x4*)&xbuf[qt][lane] = m;
    __syncthreads();
    if (!half) {
        f32x4 o = *(const f32x4*)&xbuf[qt][lane];
#pragma unroll
        for (int r = 0; r < 4; ++r) m[r] = fminf(m[r], o[r]);

        // min over the 16 target-columns within each 16-lane group
#pragma unroll
        for (int r = 0; r < 4; ++r) {
            float v = m[r];
            v = fminf(v, __shfl_xor(v, 1, 16));
            v = fminf(v, __shfl_xor(v, 2, 16));
            v = fminf(v, __shfl_xor(v, 4, 16));
            v = fminf(v, __shfl_xor(v, 8, 16));
            m[r] = v;
        }

        // leaders hold rows g*4+r: add |q|^2, clamp, sqrt, partial-sum
        if ((lane & 15) == 0) {
            int g = lane >> 4;
            float ssum = 0.0f;
#pragma unroll
            for (int r = 0; r < 4; ++r) {
                float2 qp = qry[q0 + g * 4 + r];         // L1-hot reload
                float xs = qp.x * SCALE, ys = qp.y * SCALE;
                float pn = fmaf(xs, xs, ys * ys);
                ssum += sqrtf(fmaxf(m[r] + pn, 0.0f));
            }
            psum[w * 4 + g] = ssum;
        }
    }
    __syncthreads();
    if (tid == 0) {
        float t = 0.0f;
#pragma unroll
        for (int k = 0; k < 16; ++k) t += psum[k];
        atomicAdd(out, t * INVS);
    }
}

extern "C" void kernel_launch(void* const* d_in, const int* in_sizes, int n_in,
                              void* d_out, int out_size, void* d_ws, size_t ws_size,
                              hipStream_t stream) {
    const float2* pc  = (const float2*)d_in[0];  // img_render_points
    const float2* ref = (const float2*)d_in[1];  // ref contour
    float* out = (float*)d_out;
    f16x8* tbl = (f16x8*)d_ws;                   // 512 KB used

    cc_pack_kernel<<<(2 * NPTS) / 256, 256, 0, stream>>>(pc, ref, tbl, out);
    // 2 dirs x 256 query-blocks = 512 blocks = 2/CU, 4 waves/SIMD
    cc_min_kernel<<<512, BLK, 0, stream>>>(pc, ref, tbl, out);
}